// Round 5
// baseline (174.459 us; speedup 1.0000x reference)
//
#include <hip/hip_runtime.h>

#define NN 100000   // N_SRC == N_DST
#define FD 64       // IN_SRC == IN_DST == OUT
#define NE 1250000  // E

#define RPB 128                         // dst rows per bucket
#define NBK ((NN + RPB - 1) / RPB)      // 782 buckets
#define NBP 1024                        // padded bucket count (pow2 >= NBK)
#define CAP 2048                        // fixed window per bucket (E[cnt]=1600, sd~40)
#define NTILE (NN / 16)                 // 6250 MFMA tiles per matrix

#define TPW 2                           // tiles per wave in linear part
#define NWM (NTILE / TPW)               // 3125 waves per matrix
#define LIN_GRID ((2 * NWM + 3) / 4)    // 1563 blocks (4 waves/block)

#define EPT 16                          // edges per thread in fused kplace
#define CH2 (256 * EPT)                 // 4096 edges per partition block
#define NCH2 ((NE + CH2 - 1) / CH2)     // 306 partition blocks
#define FUSE_GRID (NCH2 + LIN_GRID)     // 1869 blocks, 256 threads

typedef __attribute__((ext_vector_type(8))) short bf16x8;
typedef __attribute__((ext_vector_type(4))) float f32x4;

__device__ __forceinline__ short cvt_bf16(float f) {   // RNE
    unsigned u = __float_as_uint(f);
    return (short)((u + 0x7FFFu + ((u >> 16) & 1u)) >> 16);
}
__device__ __forceinline__ float bf2f(unsigned short u) {
    return __uint_as_float(((unsigned)u) << 16);
}

// Linear tile pair for one wave (shared by lin_place and fallback lin_both).
// Swapped mfma(wf, a): D[c][i] with col(lane&15)=i (x row), row(quad*4+r)=c.
// Each lane's acc[ct] = 4 contiguous channels of one row -> float4/ushort4 stores.
__device__ __forceinline__ void lin_wave(
    const float* __restrict__ x_src, const float* __restrict__ x_dst,
    const float* __restrict__ W_nei, const float* __restrict__ W_self,
    const float* __restrict__ b_self, unsigned short* __restrict__ hbuf,
    float* __restrict__ out, int gw, int lane)
{
    const int m    = lane & 15;
    const int quad = lane >> 4;
    const bool self = gw >= NWM;
    const int  wm   = self ? gw - NWM : gw;
    const float* __restrict__ x = self ? x_dst : x_src;
    const float* __restrict__ W = self ? W_self : W_nei;

    // all x loads for both tiles upfront: 8 independent float4 loads in flight
    const float* xb = x + (size_t)(wm * (TPW * 16) + m) * FD;
    float4 xv[TPW][4];
    #pragma unroll
    for (int t = 0; t < TPW; t++) {
        const float* xr = xb + (size_t)t * 16 * FD;
        xv[t][0] = *(const float4*)(xr + quad * 8);
        xv[t][1] = *(const float4*)(xr + quad * 8 + 4);
        xv[t][2] = *(const float4*)(xr + 32 + quad * 8);
        xv[t][3] = *(const float4*)(xr + 32 + quad * 8 + 4);
    }

    // W frags (A-operand of the swapped mfma): wf[kc][ct] = W[ct*16+m][kc*32+quad*8 ..+7]
    bf16x8 wf[2][4];
    #pragma unroll
    for (int kc = 0; kc < 2; kc++) {
        #pragma unroll
        for (int ct = 0; ct < 4; ct++) {
            const float4 w0 = *(const float4*)(W + (ct * 16 + m) * FD + kc * 32 + quad * 8);
            const float4 w1 = *(const float4*)(W + (ct * 16 + m) * FD + kc * 32 + quad * 8 + 4);
            bf16x8 f;
            f[0]=cvt_bf16(w0.x); f[1]=cvt_bf16(w0.y); f[2]=cvt_bf16(w0.z); f[3]=cvt_bf16(w0.w);
            f[4]=cvt_bf16(w1.x); f[5]=cvt_bf16(w1.y); f[6]=cvt_bf16(w1.z); f[7]=cvt_bf16(w1.w);
            wf[kc][ct] = f;
        }
    }

    float4 bv[4];
    if (self) {
        #pragma unroll
        for (int ct = 0; ct < 4; ct++)
            bv[ct] = *(const float4*)(b_self + ct * 16 + quad * 4);
    }

    #pragma unroll
    for (int t = 0; t < TPW; t++) {
        bf16x8 a0, a1;
        a0[0]=cvt_bf16(xv[t][0].x); a0[1]=cvt_bf16(xv[t][0].y);
        a0[2]=cvt_bf16(xv[t][0].z); a0[3]=cvt_bf16(xv[t][0].w);
        a0[4]=cvt_bf16(xv[t][1].x); a0[5]=cvt_bf16(xv[t][1].y);
        a0[6]=cvt_bf16(xv[t][1].z); a0[7]=cvt_bf16(xv[t][1].w);
        a1[0]=cvt_bf16(xv[t][2].x); a1[1]=cvt_bf16(xv[t][2].y);
        a1[2]=cvt_bf16(xv[t][2].z); a1[3]=cvt_bf16(xv[t][2].w);
        a1[4]=cvt_bf16(xv[t][3].x); a1[5]=cvt_bf16(xv[t][3].y);
        a1[6]=cvt_bf16(xv[t][3].z); a1[7]=cvt_bf16(xv[t][3].w);

        f32x4 acc[4];
        #pragma unroll
        for (int ct = 0; ct < 4; ct++) {
            f32x4 z = (f32x4){0.f, 0.f, 0.f, 0.f};
            z = __builtin_amdgcn_mfma_f32_16x16x32_bf16(wf[0][ct], a0, z, 0, 0, 0);
            z = __builtin_amdgcn_mfma_f32_16x16x32_bf16(wf[1][ct], a1, z, 0, 0, 0);
            acc[ct] = z;
        }

        const size_t rowbase = (size_t)(wm * (TPW * 16) + t * 16 + m) * FD;
        if (!self) {
            #pragma unroll
            for (int ct = 0; ct < 4; ct++) {
                ushort4 sv;
                sv.x = (unsigned short)cvt_bf16(acc[ct][0]);
                sv.y = (unsigned short)cvt_bf16(acc[ct][1]);
                sv.z = (unsigned short)cvt_bf16(acc[ct][2]);
                sv.w = (unsigned short)cvt_bf16(acc[ct][3]);
                *(ushort4*)(hbuf + rowbase + ct * 16 + quad * 4) = sv;
            }
        } else {
            #pragma unroll
            for (int ct = 0; ct < 4; ct++) {
                float4 v;
                v.x = acc[ct][0] + bv[ct].x;
                v.y = acc[ct][1] + bv[ct].y;
                v.z = acc[ct][2] + bv[ct].z;
                v.w = acc[ct][3] + bv[ct].w;
                *(float4*)(out + rowbase + ct * 16 + quad * 4) = v;
            }
        }
    }
}

// ---------- fused linears + edge partition in ONE dispatch ----------
// Blocks [0, NCH2): kplace on CH2 edges each (independent of linear work).
// Blocks [NCH2, FUSE_GRID): 4 waves x 2 MFMA tiles of the linears.
// The two halves touch disjoint data -> hardware overlaps them freely.
// gcursor must be zeroed by a prior stream op (hipMemsetAsync) — NOT in-kernel
// (block 0 zeroing would race against other blocks of the same dispatch).
__global__ __launch_bounds__(256) void lin_place(
    const float* __restrict__ x_src, const float* __restrict__ x_dst,
    const float* __restrict__ W_nei, const float* __restrict__ W_self,
    const float* __restrict__ b_self, unsigned short* __restrict__ hbuf,
    float* __restrict__ out,
    const int* __restrict__ src, const int* __restrict__ dst,
    const float* __restrict__ ew, int* __restrict__ gcursor,
    int2* __restrict__ sp)
{
    __shared__ int cnt[NBP];
    if (blockIdx.x < NCH2) {
        // ---- edge partition (kplace), 256 threads, EPT edges/thread ----
        const int t = threadIdx.x;
        #pragma unroll
        for (int i = 0; i < NBP / 256; i++) cnt[t + i * 256] = 0;
        __syncthreads();
        const int e0 = blockIdx.x * CH2;

        // pass 1: preload dst values (coalesced, independent), then count
        int d[EPT];
        #pragma unroll
        for (int k = 0; k < EPT; k++) {
            const int e = e0 + t + k * 256;
            d[k] = (e < NE) ? dst[e] : -1;
        }
        #pragma unroll
        for (int k = 0; k < EPT; k++)
            if (d[k] >= 0) atomicAdd(&cnt[d[k] >> 7], 1);
        __syncthreads();

        // reserve dense segments in each bucket's fixed window
        #pragma unroll
        for (int i = 0; i < NBP / 256; i++) {
            const int bb = t + i * 256;
            const int c = cnt[bb];
            cnt[bb] = c ? (bb * CAP + atomicAdd(&gcursor[bb], c)) : 0;
        }
        __syncthreads();

        // pass 2: preload src/ew, then emit (EPT stores in flight per thread)
        int s[EPT]; float w[EPT];
        #pragma unroll
        for (int k = 0; k < EPT; k++) {
            const int e = e0 + t + k * 256;
            if (e < NE) { s[k] = src[e]; w[k] = ew[e]; }
        }
        #pragma unroll
        for (int k = 0; k < EPT; k++) {
            if (d[k] >= 0) {
                const int p = atomicAdd(&cnt[d[k] >> 7], 1);
                sp[p] = make_int2(s[k] | ((d[k] & (RPB - 1)) << 17),
                                  __float_as_int(w[k]));
            }
        }
        return;
    }
    // ---- linear part ----
    const int gw = (blockIdx.x - NCH2) * 4 + (threadIdx.x >> 6);
    if (gw >= 2 * NWM) return;
    lin_wave(x_src, x_dst, W_nei, W_self, b_self, hbuf, out,
             gw, threadIdx.x & 63);
}

// ---------- standalone linears (fallback path only) ----------
__global__ __launch_bounds__(256) void lin_both(
    const float* __restrict__ x_src, const float* __restrict__ x_dst,
    const float* __restrict__ W_nei, const float* __restrict__ W_self,
    const float* __restrict__ b_self, unsigned short* __restrict__ hbuf,
    float* __restrict__ out)
{
    const int gw = blockIdx.x * 4 + (threadIdx.x >> 6);
    if (gw >= 2 * NWM) return;
    lin_wave(x_src, x_dst, W_nei, W_self, b_self, hbuf, out,
             gw, threadIdx.x & 63);
}

// ---------- fused counting-sort + gather: one block per bucket ----------
// Phase 1 (ksub-in-LDS): register-stage the bucket's sp window, histogram into
// hist[128], wave-0 scan, scatter into LDS ebuf (no sp2/rowstart globals).
// Phase 2 (gather v3 scheme): wave wv handles rows wv+8i; quad q takes edge
// k+4j+q via broadcast ds_read_b64; 16 lanes load the full 128B h-row as uint2.
// Per-row round-up reads past n hit either the NEXT row's edges (valid, finite,
// w=0) or the zeroed tail pad ebuf[cnt..cnt+15] (srow=0 -> finite h row 0, w=0).
// NOTE: w=0 masking only works if the gathered data is FINITE — uninitialized
// LDS decoding to bf16 NaN gives fmaf(NaN,0,acc)=NaN (the Round-3 bug).
__global__ __launch_bounds__(512) void sort_gather(
    const int2* __restrict__ sp, const int* __restrict__ gcursor,
    const unsigned short* __restrict__ h, float* __restrict__ out)
{
    __shared__ int2 ebuf[CAP + 16];
    __shared__ int hist[RPB];
    __shared__ int rs[RPB];
    __shared__ int cur[RPB];
    const int t = threadIdx.x;            // 0..511
    const int b = blockIdx.x;
    const int cnt = gcursor[b];
    const int s0 = b * CAP;

    if (t < RPB) hist[t] = 0;

    // register-stage this bucket's window (coalesced, 4 edges/thread)
    int2 ev[4]; int er[4];
    #pragma unroll
    for (int k = 0; k < 4; k++) {
        const int j = t + k * 512;
        if (j < cnt) { ev[k] = sp[s0 + j]; er[k] = ev[k].x >> 17; }
        else er[k] = -1;
    }
    __syncthreads();
    #pragma unroll
    for (int k = 0; k < 4; k++)
        if (er[k] >= 0) atomicAdd(&hist[er[k]], 1);
    __syncthreads();
    if (t < 64) {                         // wave 0 scans 2 bins per lane
        const int v0 = hist[2*t], v1 = hist[2*t + 1];
        const int s = v0 + v1;
        int inc = s;
        #pragma unroll
        for (int off = 1; off < 64; off <<= 1) {
            int u = __shfl_up(inc, off, 64);
            if (t >= off) inc += u;
        }
        const int ex = inc - s;
        rs[2*t]      = ex;       cur[2*t]     = ex;
        rs[2*t + 1]  = ex + v0;  cur[2*t + 1] = ex + v0;
    }
    __syncthreads();
    #pragma unroll
    for (int k = 0; k < 4; k++) {
        if (er[k] >= 0) {
            const int p = atomicAdd(&cur[er[k]], 1);
            ebuf[p] = ev[k];
        }
    }
    if (t < 16) ebuf[cnt + t] = make_int2(0, 0);  // zero the read-over tail pad
    __syncthreads();

    // phase 2: gather
    const int wv   = t >> 6;              // wave 0..7
    const int lane = t & 63;
    const int q    = lane >> 4;
    const int tc   = lane & 15;
    const unsigned tb = (unsigned)tc << 3;
    const int row0 = b * RPB;

    for (int i = 0; i < 16; i++) {
        const int r   = wv + i * 8;       // monotone in i per wave
        const int row = row0 + r;
        if (row >= NN) break;
        const int rsr = rs[r];
        const int n   = hist[r];
        float a0 = 0.f, a1 = 0.f, a2 = 0.f, a3 = 0.f;
        for (int k = 0; k < n; k += 16) {
            int2 ed[4];
            #pragma unroll
            for (int j = 0; j < 4; j++)
                ed[j] = ebuf[rsr + k + j * 4 + q];   // broadcast within quad
            uint2 dv[4]; float wv4[4];
            #pragma unroll
            for (int j = 0; j < 4; j++) {
                const unsigned off = (((unsigned)(ed[j].x & 0x1FFFF)) << 7) | tb;
                dv[j] = *(const uint2*)((const char*)h + off);
                wv4[j] = (k + j * 4 + q < n) ? __int_as_float(ed[j].y) : 0.f;
            }
            #pragma unroll
            for (int j = 0; j < 4; j++) {
                const float w = wv4[j];
                a0 = fmaf(__uint_as_float(dv[j].x << 16),         w, a0);
                a1 = fmaf(__uint_as_float(dv[j].x & 0xFFFF0000u), w, a1);
                a2 = fmaf(__uint_as_float(dv[j].y << 16),         w, a2);
                a3 = fmaf(__uint_as_float(dv[j].y & 0xFFFF0000u), w, a3);
            }
        }
        // cross-quad reduction
        a0 += __shfl_xor(a0, 16, 64); a1 += __shfl_xor(a1, 16, 64);
        a2 += __shfl_xor(a2, 16, 64); a3 += __shfl_xor(a3, 16, 64);
        a0 += __shfl_xor(a0, 32, 64); a1 += __shfl_xor(a1, 32, 64);
        a2 += __shfl_xor(a2, 32, 64); a3 += __shfl_xor(a3, 32, 64);
        if (q == 0) {                     // coalesced 256B float4 RMW
            float4* p = (float4*)(out + (size_t)row * FD + (tc << 2));
            float4 v = *p;
            v.x += a0; v.y += a1; v.z += a2; v.w += a3;
            *p = v;
        }
    }
}

// ---------- fallback (small ws): linears + atomic scatter ----------
__global__ __launch_bounds__(256) void scatter_edges(
    const unsigned short* __restrict__ h, const int* __restrict__ eidx,
    const float* __restrict__ ew, float* __restrict__ out)
{
    const int lane  = threadIdx.x & 63;
    const int gwave = (int)((blockIdx.x * blockDim.x + threadIdx.x) >> 6);
    const int nwave = (int)((gridDim.x * blockDim.x) >> 6);
    const int* __restrict__ src = eidx;
    const int* __restrict__ dst = eidx + NE;
    for (int e = gwave; e < NE; e += nwave) {
        const float v = bf2f(h[(size_t)src[e] * FD + lane]) * ew[e];
        atomicAdd(out + (size_t)dst[e] * FD + lane, v);
    }
}

extern "C" void kernel_launch(void* const* d_in, const int* in_sizes, int n_in,
                              void* d_out, int out_size, void* d_ws, size_t ws_size,
                              hipStream_t stream)
{
    const float* x_src  = (const float*)d_in[0];
    const float* x_dst  = (const float*)d_in[1];
    const int*   eidx   = (const int*)  d_in[2];   // [2,E]: src row then dst row
    const float* ew     = (const float*)d_in[3];
    const float* W_nei  = (const float*)d_in[4];
    const float* W_self = (const float*)d_in[5];
    const float* b_self = (const float*)d_in[6];
    float* out = (float*)d_out;

    const int* src = eidx;
    const int* dst = eidx + NE;

    // workspace layout (16B aligned); h MUST stay at ws base (pad-read bound)
    char* ws = (char*)d_ws;
    size_t off = 0;
    auto alloc = [&](size_t bytes) { char* p = ws + off; off += (bytes + 15) & ~(size_t)15; return p; };
    unsigned short* h = (unsigned short*)alloc((size_t)NN * FD * sizeof(unsigned short)); // 12.8 MB
    int*  gcursor  = (int*) alloc((size_t)NBP * sizeof(int));
    int2* sp       = (int2*)alloc((size_t)NBP * CAP * sizeof(int2));  // 16 MB
    const size_t need_main = off;
    const size_t need_h    = (size_t)NN * FD * sizeof(unsigned short);

    if (ws_size >= need_main) {
        hipMemsetAsync(gcursor, 0, (size_t)NBP * sizeof(int), stream);
        lin_place<<<FUSE_GRID, 256, 0, stream>>>(x_src, x_dst, W_nei, W_self,
                                                 b_self, h, out, src, dst, ew,
                                                 gcursor, sp);
        sort_gather<<<NBK, 512, 0, stream>>>(sp, gcursor, h, out);
    } else if (ws_size >= need_h) {
        lin_both<<<LIN_GRID, 256, 0, stream>>>(x_src, x_dst, W_nei, W_self,
                                               b_self, h, out);
        scatter_edges<<<2048, 256, 0, stream>>>(h, eidx, ew, out);
    }
}

// Round 6
// 171.392 us; speedup vs baseline: 1.0179x; 1.0179x over previous
//
#include <hip/hip_runtime.h>

#define NN 100000   // N_SRC == N_DST
#define FD 64       // IN_SRC == IN_DST == OUT
#define NE 1250000  // E

#define RPB 128                         // dst rows per bucket
#define NBK ((NN + RPB - 1) / RPB)      // 782 buckets
#define NBP 1024                        // padded bucket count (pow2 >= NBK)
#define CAP 2048                        // fixed window per bucket (E[cnt]=1600, sd~40)
#define CH  8192                        // edges per partition block
#define NCH ((NE + CH - 1) / CH)        // 153 partition blocks
#define NTILE (NN / 16)                 // 6250 MFMA tiles per matrix

#define TPW 2                           // tiles per wave in lin_both
#define NWM (NTILE / TPW)               // 3125 waves per matrix
#define LIN_GRID ((2 * NWM + 3) / 4)    // 1563 blocks (4 waves/block)

typedef __attribute__((ext_vector_type(8))) short bf16x8;
typedef __attribute__((ext_vector_type(4))) float f32x4;

__device__ __forceinline__ short cvt_bf16(float f) {   // RNE
    unsigned u = __float_as_uint(f);
    return (short)((u + 0x7FFFu + ((u >> 16) & 1u)) >> 16);
}
__device__ __forceinline__ float bf2f(unsigned short u) {
    return __uint_as_float(((unsigned)u) << 16);
}

// ---------- fused linears: 2 tiles/wave, W-in-reg, swapped-operand MFMA ----------
// Swapped mfma(wf, a): D[c][i] with col(lane&15)=i (x row), row(quad*4+r)=c.
// Each lane's acc[ct] = 4 contiguous channels of one row -> float4/ushort4 stores.
// Block 0 also zeroes gcursor (completes before kplace by stream order).
// NOTE (R5 lesson): do NOT merge kplace into this dispatch — both halves are
// issue-bound on the same pipes, merged time = sum not max (52.6us vs ~50 split).
__global__ __launch_bounds__(256) void lin_both(
    const float* __restrict__ x_src, const float* __restrict__ x_dst,
    const float* __restrict__ W_nei, const float* __restrict__ W_self,
    const float* __restrict__ b_self, unsigned short* __restrict__ hbuf,
    float* __restrict__ out, int* __restrict__ gcur)
{
    if (gcur && blockIdx.x == 0) {
        #pragma unroll
        for (int i = 0; i < NBP / 256; i++) gcur[threadIdx.x + i * 256] = 0;
    }
    const int lane = threadIdx.x & 63;
    const int m    = lane & 15;
    const int quad = lane >> 4;
    const int gw   = blockIdx.x * 4 + (threadIdx.x >> 6);
    if (gw >= 2 * NWM) return;
    const bool self = gw >= NWM;
    const int  wm   = self ? gw - NWM : gw;
    const float* __restrict__ x = self ? x_dst : x_src;
    const float* __restrict__ W = self ? W_self : W_nei;

    // all x loads for both tiles upfront: 8 independent float4 loads in flight
    const float* xb = x + (size_t)(wm * (TPW * 16) + m) * FD;
    float4 xv[TPW][4];
    #pragma unroll
    for (int t = 0; t < TPW; t++) {
        const float* xr = xb + (size_t)t * 16 * FD;
        xv[t][0] = *(const float4*)(xr + quad * 8);
        xv[t][1] = *(const float4*)(xr + quad * 8 + 4);
        xv[t][2] = *(const float4*)(xr + 32 + quad * 8);
        xv[t][3] = *(const float4*)(xr + 32 + quad * 8 + 4);
    }

    // W frags (A-operand of the swapped mfma): wf[kc][ct] = W[ct*16+m][kc*32+quad*8 ..+7]
    bf16x8 wf[2][4];
    #pragma unroll
    for (int kc = 0; kc < 2; kc++) {
        #pragma unroll
        for (int ct = 0; ct < 4; ct++) {
            const float4 w0 = *(const float4*)(W + (ct * 16 + m) * FD + kc * 32 + quad * 8);
            const float4 w1 = *(const float4*)(W + (ct * 16 + m) * FD + kc * 32 + quad * 8 + 4);
            bf16x8 f;
            f[0]=cvt_bf16(w0.x); f[1]=cvt_bf16(w0.y); f[2]=cvt_bf16(w0.z); f[3]=cvt_bf16(w0.w);
            f[4]=cvt_bf16(w1.x); f[5]=cvt_bf16(w1.y); f[6]=cvt_bf16(w1.z); f[7]=cvt_bf16(w1.w);
            wf[kc][ct] = f;
        }
    }

    float4 bv[4];
    if (self) {
        #pragma unroll
        for (int ct = 0; ct < 4; ct++)
            bv[ct] = *(const float4*)(b_self + ct * 16 + quad * 4);
    }

    #pragma unroll
    for (int t = 0; t < TPW; t++) {
        bf16x8 a0, a1;
        a0[0]=cvt_bf16(xv[t][0].x); a0[1]=cvt_bf16(xv[t][0].y);
        a0[2]=cvt_bf16(xv[t][0].z); a0[3]=cvt_bf16(xv[t][0].w);
        a0[4]=cvt_bf16(xv[t][1].x); a0[5]=cvt_bf16(xv[t][1].y);
        a0[6]=cvt_bf16(xv[t][1].z); a0[7]=cvt_bf16(xv[t][1].w);
        a1[0]=cvt_bf16(xv[t][2].x); a1[1]=cvt_bf16(xv[t][2].y);
        a1[2]=cvt_bf16(xv[t][2].z); a1[3]=cvt_bf16(xv[t][2].w);
        a1[4]=cvt_bf16(xv[t][3].x); a1[5]=cvt_bf16(xv[t][3].y);
        a1[6]=cvt_bf16(xv[t][3].z); a1[7]=cvt_bf16(xv[t][3].w);

        f32x4 acc[4];
        #pragma unroll
        for (int ct = 0; ct < 4; ct++) {
            f32x4 z = (f32x4){0.f, 0.f, 0.f, 0.f};
            z = __builtin_amdgcn_mfma_f32_16x16x32_bf16(wf[0][ct], a0, z, 0, 0, 0);
            z = __builtin_amdgcn_mfma_f32_16x16x32_bf16(wf[1][ct], a1, z, 0, 0, 0);
            acc[ct] = z;
        }

        const size_t rowbase = (size_t)(wm * (TPW * 16) + t * 16 + m) * FD;
        if (!self) {
            #pragma unroll
            for (int ct = 0; ct < 4; ct++) {
                ushort4 sv;
                sv.x = (unsigned short)cvt_bf16(acc[ct][0]);
                sv.y = (unsigned short)cvt_bf16(acc[ct][1]);
                sv.z = (unsigned short)cvt_bf16(acc[ct][2]);
                sv.w = (unsigned short)cvt_bf16(acc[ct][3]);
                *(ushort4*)(hbuf + rowbase + ct * 16 + quad * 4) = sv;
            }
        } else {
            #pragma unroll
            for (int ct = 0; ct < 4; ct++) {
                float4 v;
                v.x = acc[ct][0] + bv[ct].x;
                v.y = acc[ct][1] + bv[ct].y;
                v.z = acc[ct][2] + bv[ct].z;
                v.w = acc[ct][3] + bv[ct].w;
                *(float4*)(out + rowbase + ct * 16 + quad * 4) = v;
            }
        }
    }
}

// ---------- partition edges into fixed-capacity bucket windows ----------
// 1024 threads (16 waves/block, 2 blocks/CU), 8 edges/thread preloaded for ILP.
__global__ __launch_bounds__(1024) void kplace(
    const int* __restrict__ src, const int* __restrict__ dst,
    const float* __restrict__ ew, int* __restrict__ gcursor,
    int2* __restrict__ sp)
{
    __shared__ int cnt[NBP];
    const int t = threadIdx.x;            // 0..1023
    if (t < NBP) cnt[t] = 0;
    __syncthreads();
    const int e0 = blockIdx.x * CH;

    // pass 1: preload 8 dst values (coalesced, independent), then count
    int d[8];
    #pragma unroll
    for (int k = 0; k < 8; k++) {
        const int e = e0 + t + k * 1024;
        d[k] = (e < NE) ? dst[e] : -1;
    }
    #pragma unroll
    for (int k = 0; k < 8; k++)
        if (d[k] >= 0) atomicAdd(&cnt[d[k] >> 7], 1);
    __syncthreads();

    // reserve dense segments in this bucket's fixed window
    if (t < NBP) {
        const int c = cnt[t];
        cnt[t] = c ? (t * CAP + atomicAdd(&gcursor[t], c)) : 0;
    }
    __syncthreads();

    // pass 2: preload src/ew, then emit (8 stores in flight per thread)
    int s[8]; float w[8];
    #pragma unroll
    for (int k = 0; k < 8; k++) {
        const int e = e0 + t + k * 1024;
        if (e < NE) { s[k] = src[e]; w[k] = ew[e]; }
    }
    #pragma unroll
    for (int k = 0; k < 8; k++) {
        if (d[k] >= 0) {
            const int p = atomicAdd(&cnt[d[k] >> 7], 1);
            sp[p] = make_int2(s[k] | ((d[k] & (RPB - 1)) << 17),
                              __float_as_int(w[k]));
        }
    }
}

// ---------- fused counting-sort + gather v4: quad-per-row ----------
// Phase 1 (ksub-in-LDS): register-stage the bucket's sp window, histogram into
// hist[128], wave-0 scan, scatter into LDS ebuf (no sp2/rowstart globals).
// Phase 2 (quad-per-row): wave wv, quad q owns row i*32+wv*4+q. Its 16 lanes
// gather whole 128B h-rows (uint2 each, 4 edges in flight) and accumulate the
// row's FULL column sums locally -> no cross-quad shuffle reduction; the out
// RMW uses all 64 lanes (4 consecutive rows = 1KB contiguous per wave).
// Pad reads (n rounded to 4) stay <= rs[r]+n+3 < cnt+16: slots within cnt are
// the next row's edges (valid srow, w masked 0); slots past cnt are the zeroed
// tail pad (srow=0 -> finite h row 0, w=0). w=0 masking requires FINITE data —
// uninitialized LDS decoding to bf16 NaN gives fmaf(NaN,0,acc)=NaN (R3 bug).
__global__ __launch_bounds__(512) void sort_gather(
    const int2* __restrict__ sp, const int* __restrict__ gcursor,
    const unsigned short* __restrict__ h, float* __restrict__ out)
{
    __shared__ int2 ebuf[CAP + 16];
    __shared__ int hist[RPB];
    __shared__ int rs[RPB];
    __shared__ int cur[RPB];
    const int t = threadIdx.x;            // 0..511
    const int b = blockIdx.x;
    const int cnt = gcursor[b];
    const int s0 = b * CAP;

    if (t < RPB) hist[t] = 0;

    // register-stage this bucket's window (coalesced, 4 edges/thread)
    int2 ev[4]; int er[4];
    #pragma unroll
    for (int k = 0; k < 4; k++) {
        const int j = t + k * 512;
        if (j < cnt) { ev[k] = sp[s0 + j]; er[k] = ev[k].x >> 17; }
        else er[k] = -1;
    }
    __syncthreads();
    #pragma unroll
    for (int k = 0; k < 4; k++)
        if (er[k] >= 0) atomicAdd(&hist[er[k]], 1);
    __syncthreads();
    if (t < 64) {                         // wave 0 scans 2 bins per lane
        const int v0 = hist[2*t], v1 = hist[2*t + 1];
        const int s = v0 + v1;
        int inc = s;
        #pragma unroll
        for (int off = 1; off < 64; off <<= 1) {
            int u = __shfl_up(inc, off, 64);
            if (t >= off) inc += u;
        }
        const int ex = inc - s;
        rs[2*t]      = ex;       cur[2*t]     = ex;
        rs[2*t + 1]  = ex + v0;  cur[2*t + 1] = ex + v0;
    }
    __syncthreads();
    #pragma unroll
    for (int k = 0; k < 4; k++) {
        if (er[k] >= 0) {
            const int p = atomicAdd(&cur[er[k]], 1);
            ebuf[p] = ev[k];
        }
    }
    if (t < 16) ebuf[cnt + t] = make_int2(0, 0);  // zero the read-over tail pad
    __syncthreads();

    // phase 2: quad-per-row gather
    const int wv   = t >> 6;              // wave 0..7
    const int lane = t & 63;
    const int q    = lane >> 4;           // quad -> row within group of 4
    const int tc   = lane & 15;           // column group: cols 4tc..4tc+3
    const unsigned tb = (unsigned)tc << 3;
    const int row0 = b * RPB;

    #pragma unroll
    for (int i = 0; i < 4; i++) {
        const int r   = i * 32 + wv * 4 + q;   // 32 rows in flight per pass
        const int row = row0 + r;
        if (row >= NN) continue;               // per-lane guard (r varies in wave)
        const int rsr = rs[r];
        const int n   = hist[r];
        float a0 = 0.f, a1 = 0.f, a2 = 0.f, a3 = 0.f;
        for (int k = 0; k < n; k += 4) {       // divergent across quads: exec-masked
            int2 ed[4];
            #pragma unroll
            for (int j = 0; j < 4; j++)
                ed[j] = ebuf[rsr + k + j];     // broadcast within quad
            uint2 dv[4]; float wv4[4];
            #pragma unroll
            for (int j = 0; j < 4; j++) {      // 4 gathers in flight per quad
                const unsigned off = (((unsigned)(ed[j].x & 0x1FFFF)) << 7) | tb;
                dv[j] = *(const uint2*)((const char*)h + off);
                wv4[j] = (k + j < n) ? __int_as_float(ed[j].y) : 0.f;
            }
            #pragma unroll
            for (int j = 0; j < 4; j++) {
                const float w = wv4[j];
                a0 = fmaf(__uint_as_float(dv[j].x << 16),         w, a0);
                a1 = fmaf(__uint_as_float(dv[j].x & 0xFFFF0000u), w, a1);
                a2 = fmaf(__uint_as_float(dv[j].y << 16),         w, a2);
                a3 = fmaf(__uint_as_float(dv[j].y & 0xFFFF0000u), w, a3);
            }
        }
        // no cross-quad reduction needed: quad owns the whole row.
        float4* p = (float4*)(out + (size_t)row * FD + (tc << 2));
        float4 v = *p;
        v.x += a0; v.y += a1; v.z += a2; v.w += a3;
        *p = v;
    }
}

// ---------- fallback (small ws): linears + atomic scatter ----------
__global__ __launch_bounds__(256) void scatter_edges(
    const unsigned short* __restrict__ h, const int* __restrict__ eidx,
    const float* __restrict__ ew, float* __restrict__ out)
{
    const int lane  = threadIdx.x & 63;
    const int gwave = (int)((blockIdx.x * blockDim.x + threadIdx.x) >> 6);
    const int nwave = (int)((gridDim.x * blockDim.x) >> 6);
    const int* __restrict__ src = eidx;
    const int* __restrict__ dst = eidx + NE;
    for (int e = gwave; e < NE; e += nwave) {
        const float v = bf2f(h[(size_t)src[e] * FD + lane]) * ew[e];
        atomicAdd(out + (size_t)dst[e] * FD + lane, v);
    }
}

extern "C" void kernel_launch(void* const* d_in, const int* in_sizes, int n_in,
                              void* d_out, int out_size, void* d_ws, size_t ws_size,
                              hipStream_t stream)
{
    const float* x_src  = (const float*)d_in[0];
    const float* x_dst  = (const float*)d_in[1];
    const int*   eidx   = (const int*)  d_in[2];   // [2,E]: src row then dst row
    const float* ew     = (const float*)d_in[3];
    const float* W_nei  = (const float*)d_in[4];
    const float* W_self = (const float*)d_in[5];
    const float* b_self = (const float*)d_in[6];
    float* out = (float*)d_out;

    const int* src = eidx;
    const int* dst = eidx + NE;

    // workspace layout (16B aligned); h MUST stay at ws base (pad-read bound)
    char* ws = (char*)d_ws;
    size_t off = 0;
    auto alloc = [&](size_t bytes) { char* p = ws + off; off += (bytes + 15) & ~(size_t)15; return p; };
    unsigned short* h = (unsigned short*)alloc((size_t)NN * FD * sizeof(unsigned short)); // 12.8 MB
    int*  gcursor  = (int*) alloc((size_t)NBP * sizeof(int));
    int2* sp       = (int2*)alloc((size_t)NBP * CAP * sizeof(int2));  // 16 MB
    const size_t need_main = off;
    const size_t need_h    = (size_t)NN * FD * sizeof(unsigned short);

    if (ws_size >= need_main) {
        lin_both<<<LIN_GRID, 256, 0, stream>>>(x_src, x_dst, W_nei, W_self,
                                               b_self, h, out, gcursor);
        kplace<<<NCH, 1024, 0, stream>>>(src, dst, ew, gcursor, sp);
        sort_gather<<<NBK, 512, 0, stream>>>(sp, gcursor, h, out);
    } else if (ws_size >= need_h) {
        lin_both<<<LIN_GRID, 256, 0, stream>>>(x_src, x_dst, W_nei, W_self,
                                               b_self, h, out, nullptr);
        scatter_edges<<<2048, 256, 0, stream>>>(h, eidx, ew, out);
    }
}